// Round 8
// baseline (355.196 us; speedup 1.0000x reference)
//
#include <hip/hip_runtime.h>
#include <math.h>

// ---------------------------------------------------------------------------
// GAT 2-layer + mean-pool + classifier.
//  - CSR(dst): bucketed two-pass build (multisplit), LDS-staged coalesced
//    partition (R2).  R8: CHUNKE 4096 (2x blocks, halved LDS -> occupancy).
//  - softmax denominators factor out; no segment-max (logits O(1), fp32 safe)
//  - message tables bf16
//  - aggregation: ONE lane-group per dst (R1 config)
//  - gemm2 fused into agg1 (R6), 64-dst supertile (R7).  R8: B-fragments
//    read from GLOBAL w2b (L1-resident, 20KB, block-invariant) -- Bs2 LDS
//    staging deleted, LDS 39.4->17.4KB (R7 diagnosis: occupancy 25% capped
//    gather BW at 2.95 vs 3.36 TB/s).
//  - Pool via wave shuffle butterfly (R6).
//  - GEMM1: MFMA 16x16x32 bf16; a_src/a_dst folded as extra B columns
//    (bf16 hi/lo split, R3).
// ---------------------------------------------------------------------------

typedef __attribute__((ext_vector_type(8))) short bf16x8;
typedef __attribute__((ext_vector_type(4))) float f32x4;

__device__ __forceinline__ unsigned f2bf_rne(float x){
  unsigned u = __float_as_uint(x);
  return (u + 0x7fffu + ((u >> 16) & 1u)) >> 16;
}
__device__ __forceinline__ unsigned pk_bf2(float a, float b){
  return f2bf_rne(a) | (f2bf_rne(b) << 16);
}
__device__ __forceinline__ void unpack8(uint4 q, float* f){
  f[0] = __uint_as_float(q.x << 16);
  f[1] = __uint_as_float(q.x & 0xffff0000u);
  f[2] = __uint_as_float(q.y << 16);
  f[3] = __uint_as_float(q.y & 0xffff0000u);
  f[4] = __uint_as_float(q.z << 16);
  f[5] = __uint_as_float(q.z & 0xffff0000u);
  f[6] = __uint_as_float(q.w << 16);
  f[7] = __uint_as_float(q.w & 0xffff0000u);
}

// ---------------- bucketed CSR build ----------------

#define CHUNKE 4096

__global__ __launch_bounds__(256) void k_bucketcount(
    const int* __restrict__ dst, int* __restrict__ bcnt, int e, int NB)
{
  __shared__ int hcnt[512];
  const int tid = threadIdx.x;
  for (int b = tid; b < 512; b += 256) hcnt[b] = 0;
  __syncthreads();
  const int lo = blockIdx.x * CHUNKE;
  const int hi = min(lo + CHUNKE, e);
  for (int i = lo + tid; i < hi; i += 256)
    atomicAdd(&hcnt[dst[i] >> 8], 1);
  __syncthreads();
  for (int b = tid; b < NB; b += 256)
    if (hcnt[b]) atomicAdd(&bcnt[b], hcnt[b]);
}

// block 0: bucket scan.  block 1: wa1 att columns + W2b [80][128] bf16.
__global__ __launch_bounds__(512) void k_bucketscan(
    const int* __restrict__ bcnt, int* __restrict__ bbase,
    int* __restrict__ cur, int* __restrict__ off, int e, int n, int NB,
    const float* __restrict__ W1, const float* __restrict__ as1w,
    const float* __restrict__ ad1w,
    const float* __restrict__ W2, const float* __restrict__ as2w,
    const float* __restrict__ ad2w,
    unsigned short* __restrict__ wa1, unsigned short* __restrict__ w2b)
{
  const int t = threadIdx.x;

  if (blockIdx.x == 1){
    for (int i = t; i < 16 * 128; i += 512) w2b[64 * 128 + i] = 0;
    __syncthreads();
    {
      int k = t >> 2, j = t & 3;
      float ds = 0.f, dd = 0.f;
      for (int cc = 0; cc < 32; ++cc){
        float wv = W1[k * 128 + j * 32 + cc];
        ds = fmaf(wv, as1w[j * 32 + cc], ds);
        dd = fmaf(wv, ad1w[j * 32 + cc], dd);
      }
      unsigned hs_ = f2bf_rne(ds); float hsf = __uint_as_float(hs_ << 16);
      unsigned ls_ = f2bf_rne(ds - hsf);
      unsigned hd_ = f2bf_rne(dd); float hdf = __uint_as_float(hd_ << 16);
      unsigned ld_ = f2bf_rne(dd - hdf);
      wa1[(j     ) * 128 + k] = (unsigned short)hs_;
      wa1[(j + 4 ) * 128 + k] = (unsigned short)ls_;
      wa1[(j + 8 ) * 128 + k] = (unsigned short)hd_;
      wa1[(j + 12) * 128 + k] = (unsigned short)ld_;
    }
    for (int idx = t; idx < 64 * 128; idx += 512){
      int col = idx & 63, k = idx >> 6;
      w2b[col * 128 + k] = (unsigned short)f2bf_rne(W2[k * 64 + col]);
    }
    if (t < 128){
      int k = t;
      float ds = 0.f, dd = 0.f;
      for (int cc = 0; cc < 64; ++cc){
        float wv = W2[k * 64 + cc];
        ds = fmaf(wv, as2w[cc], ds);
        dd = fmaf(wv, ad2w[cc], dd);
      }
      unsigned hs_ = f2bf_rne(ds); float hsf = __uint_as_float(hs_ << 16);
      unsigned ls_ = f2bf_rne(ds - hsf);
      unsigned hd_ = f2bf_rne(dd); float hdf = __uint_as_float(hd_ << 16);
      unsigned ld_ = f2bf_rne(dd - hdf);
      w2b[(64 +  0) * 128 + k] = (unsigned short)hs_;
      w2b[(64 +  4) * 128 + k] = (unsigned short)ls_;
      w2b[(64 +  8) * 128 + k] = (unsigned short)hd_;
      w2b[(64 + 12) * 128 + k] = (unsigned short)ld_;
    }
    return;
  }

  __shared__ int sh[512];
  int v = (t < NB) ? bcnt[t] : 0;
  sh[t] = v;
  __syncthreads();
  for (int o = 1; o < 512; o <<= 1){
    int x = (t >= o) ? sh[t - o] : 0;
    __syncthreads();
    sh[t] += x;
    __syncthreads();
  }
  if (t < NB){
    int excl = sh[t] - v;
    bbase[t] = excl;
    cur[t]   = excl;
  }
  if (t == 0) off[n] = e;
}

// LDS-staged multisplit partition (coalesced writeout).
__global__ __launch_bounds__(256) void k_partition(
    const int* __restrict__ src, const int* __restrict__ dst,
    int* __restrict__ cur, unsigned* __restrict__ packed, int e, int NB)
{
  __shared__ unsigned       recs[CHUNKE];   // 16 KB
  __shared__ unsigned short bkt[CHUNKE];    //  8 KB
  __shared__ int hcnt[512];
  __shared__ int hoff[512];
  __shared__ int hbase[512];

  const int tid = threadIdx.x;
  const int lo  = blockIdx.x * CHUNKE;
  const int hi  = min(lo + CHUNKE, e);
  const int cnt = hi - lo;

  hcnt[tid] = 0; hcnt[tid + 256] = 0;
  __syncthreads();
  for (int i = lo + tid; i < hi; i += 256)
    atomicAdd(&hcnt[dst[i] >> 8], 1);
  __syncthreads();

  hoff[tid] = hcnt[tid]; hoff[tid + 256] = hcnt[tid + 256];
  __syncthreads();
  for (int o = 1; o < 512; o <<= 1){
    int x0 = (tid >= o)       ? hoff[tid - o]       : 0;
    int x1 = (tid + 256 >= o) ? hoff[tid + 256 - o] : 0;
    __syncthreads();
    hoff[tid] += x0; hoff[tid + 256] += x1;
    __syncthreads();
  }

  int c0 = hcnt[tid], c1 = hcnt[tid + 256];
  int e0 = hoff[tid] - c0, e1 = hoff[tid + 256] - c1;
  hbase[tid]       = c0 ? atomicAdd(&cur[tid], c0)       : 0;
  hbase[tid + 256] = c1 ? atomicAdd(&cur[tid + 256], c1) : 0;
  __syncthreads();
  hoff[tid] = e0; hoff[tid + 256] = e1;
  hcnt[tid] = 0;  hcnt[tid + 256] = 0;
  __syncthreads();

  for (int i = lo + tid; i < hi; i += 256){
    int d = dst[i];
    int b = d >> 8;
    int p = hoff[b] + atomicAdd(&hcnt[b], 1);
    recs[p] = (unsigned)src[i] | ((unsigned)(d & 255) << 17);
    bkt[p]  = (unsigned short)b;
  }
  __syncthreads();

  for (int t = tid; t < cnt; t += 256){
    int b = bkt[t];
    packed[hbase[b] + t - hoff[b]] = recs[t];
  }
}

__global__ __launch_bounds__(256) void k_bucketbuild(
    const unsigned* __restrict__ packed, const int* __restrict__ bbase,
    const int* __restrict__ bcnt, int* __restrict__ off,
    int* __restrict__ csr, int n)
{
  __shared__ int lcnt[256];
  __shared__ int loff[256];
  const int b    = blockIdx.x;
  const int tid  = threadIdx.x;
  const int seg0 = bbase[b];
  const int scnt = bcnt[b];

  lcnt[tid] = 0;
  __syncthreads();
  for (int i = tid; i < scnt; i += 256)
    atomicAdd(&lcnt[packed[seg0 + i] >> 17], 1);
  __syncthreads();
  int v = lcnt[tid];
  loff[tid] = v;
  __syncthreads();
  for (int o = 1; o < 256; o <<= 1){
    int x = (tid >= o) ? loff[tid - o] : 0;
    __syncthreads();
    loff[tid] += x;
    __syncthreads();
  }
  int excl = loff[tid] - v;
  __syncthreads();
  loff[tid] = excl;
  lcnt[tid] = 0;
  int d = (b << 8) + tid;
  if (d < n) off[d] = seg0 + excl;
  __syncthreads();
  for (int i = tid; i < scnt; i += 256){
    unsigned rec = packed[seg0 + i];
    int doff = rec >> 17;
    int s    = rec & 0x1FFFF;
    int p    = atomicAdd(&lcnt[doff], 1);
    csr[seg0 + loff[doff] + p] = s;
  }
}

// ---------------- MFMA GEMM (X @ W | W@att columns) -- conv1 ----------------

template<int OUTC, int HEADS, bool XBF16, typename XT>
__global__ __launch_bounds__(256) void k_gemm_mfma(
    const XT* __restrict__ X, const float* __restrict__ W,
    const unsigned short* __restrict__ WATT,
    unsigned short* __restrict__ H, float* __restrict__ ASRC,
    float* __restrict__ ADST, int n)
{
  constexpr int K  = 128;
  constexpr int KC = 32;
  constexpr int CT = OUTC / 16;
  constexpr int CTX = CT + 1;
  constexpr int RT = 16 / CT;
  constexpr int WROWS = RT * 16;
  constexpr int BROWS = WROWS * 4;

  __shared__ unsigned short Bs[OUTC + 16][K + 8];
  __shared__ unsigned short As[BROWS][KC + 8];

  const int tid   = threadIdx.x;
  const int lane  = tid & 63;
  const int c15   = lane & 15;
  const int quad  = lane >> 4;
  const int warow = (tid >> 6) * WROWS;
  const int row0  = blockIdx.x * BROWS;

  f32x4 acc[CTX][RT];
  #pragma unroll
  for (int ct = 0; ct < CTX; ++ct)
    #pragma unroll
    for (int t = 0; t < RT; ++t)
      #pragma unroll
      for (int r = 0; r < 4; ++r) acc[ct][t][r] = 0.f;

  for (int idx = tid; idx < K * OUTC / 4; idx += 256){
    int k  = idx / (OUTC / 4);
    int c4 = (idx % (OUTC / 4)) * 4;
    float4 v = *(const float4*)&W[(size_t)k * OUTC + c4];
    Bs[c4 + 0][k] = (unsigned short)f2bf_rne(v.x);
    Bs[c4 + 1][k] = (unsigned short)f2bf_rne(v.y);
    Bs[c4 + 2][k] = (unsigned short)f2bf_rne(v.z);
    Bs[c4 + 3][k] = (unsigned short)f2bf_rne(v.w);
  }
  for (int idx = tid; idx < 16 * (K / 8); idx += 256){
    int rr = idx >> 4;
    int q  = idx & 15;
    *(uint4*)&Bs[OUTC + rr][q * 8] = *(const uint4*)&WATT[rr * K + q * 8];
  }

  for (int kc = 0; kc < K; kc += KC){
    if (XBF16){
      for (int idx = tid; idx < BROWS * (KC / 8); idx += 256){
        int rr = idx / (KC / 8);
        int q  = idx % (KC / 8);
        int row = row0 + rr;
        uint4 v = make_uint4(0, 0, 0, 0);
        if (row < n) v = *(const uint4*)((const unsigned short*)X + (size_t)row * K + kc + q * 8);
        *(uint4*)&As[rr][q * 8] = v;
      }
    } else {
      for (int idx = tid; idx < BROWS * (KC / 4); idx += 256){
        int rr = idx / (KC / 4);
        int q  = idx % (KC / 4);
        int row = row0 + rr;
        float4 v = make_float4(0.f, 0.f, 0.f, 0.f);
        if (row < n) v = *(const float4*)((const float*)X + (size_t)row * K + kc + q * 4);
        *(uint2*)&As[rr][q * 4] = make_uint2(pk_bf2(v.x, v.y), pk_bf2(v.z, v.w));
      }
    }
    __syncthreads();

    bf16x8 af[RT];
    #pragma unroll
    for (int t = 0; t < RT; ++t)
      af[t] = *(const bf16x8*)&As[warow + t * 16 + c15][8 * quad];
    #pragma unroll
    for (int ct = 0; ct < CTX; ++ct){
      bf16x8 bfr = *(const bf16x8*)&Bs[ct * 16 + c15][kc + 8 * quad];
      #pragma unroll
      for (int t = 0; t < RT; ++t)
        acc[ct][t] = __builtin_amdgcn_mfma_f32_16x16x32_bf16(af[t], bfr, acc[ct][t], 0, 0, 0);
    }
    __syncthreads();
  }

  #pragma unroll
  for (int t = 0; t < RT; ++t){
    #pragma unroll
    for (int r = 0; r < 4; ++r){
      int row = row0 + warow + t * 16 + quad * 4 + r;
      float av = acc[CT][t][r];
      av += __shfl_xor(av, 4);
      if (row < n){
        #pragma unroll
        for (int ct = 0; ct < CT; ++ct)
          H[(size_t)row * OUTC + ct * 16 + c15] = (unsigned short)f2bf_rne(acc[ct][t][r]);
        if (c15 < HEADS)                      ASRC[row * HEADS + c15] = av;
        else if (c15 >= 8 && c15 < 8 + HEADS) ADST[row * HEADS + c15 - 8] = av;
      }
    }
  }
}

// ---------------- conv1 aggregate + bias + ELU + FUSED conv2 GEMM ----------
// 64-dst supertile (R7).  R8: phase 2 reads B-fragments directly from
// global w2b (20KB, block-invariant -> L1-resident); no Bs2 staging.

__global__ __launch_bounds__(256) void k_agg1_fused(
    const unsigned short* __restrict__ Hmsg, const float* __restrict__ ASRC,
    const float* __restrict__ ADST, const int* __restrict__ off,
    const int* __restrict__ csr, const float* __restrict__ bias,
    const unsigned short* __restrict__ W2b,
    unsigned short* __restrict__ H2, float* __restrict__ AS2,
    float* __restrict__ AD2, int n)
{
  __shared__ unsigned short Ht[64][136];

  const int tid = threadIdx.x;
  const int cl  = tid & 15;
  const int c0  = cl * 8;
  const int h   = cl >> 2;                  // c0 / 32
  const int ld  = tid >> 4;                 // 0..15
  const int d0  = (int)blockIdx.x * 64;
  const uint4* Hv = (const uint4*)Hmsg;

  float bv[8];
  #pragma unroll
  for (int j = 0; j < 8; ++j) bv[j] = bias[c0 + j];

  #pragma unroll 1
  for (int it = 0; it < 4; ++it){
    const int row = it * 16 + ld;
    const int d   = d0 + row;
    if (d >= n) break;

    const float adst = ADST[d * 4 + h];

    float acc[8];
    float wsum;
    {
      float t = ASRC[d * 4 + h] + adst;
      float w = __expf(fmaxf(t, 0.2f * t));
      float f[8];
      unpack8(Hv[d * 16 + cl], f);
      #pragma unroll
      for (int j = 0; j < 8; ++j) acc[j] = w * f[j];
      wsum = w;
    }

    const int s0   = off[d];
    const int cnt  = off[d + 1] - s0;
    const int full = cnt & ~7;

    for (int p = 0; p < full; p += 8){
      int idx[8];
      #pragma unroll
      for (int j = 0; j < 8; ++j) idx[j] = csr[s0 + p + j];
      float av[8];
      #pragma unroll
      for (int j = 0; j < 8; ++j) av[j] = ASRC[idx[j] * 4 + h];
      uint4 hq[8];
      #pragma unroll
      for (int j = 0; j < 8; ++j) hq[j] = Hv[idx[j] * 16 + cl];
      #pragma unroll
      for (int j = 0; j < 8; ++j){
        float t = av[j] + adst;
        float w = __expf(fmaxf(t, 0.2f * t));
        float f[8];
        unpack8(hq[j], f);
        #pragma unroll
        for (int q = 0; q < 8; ++q) acc[q] = fmaf(w, f[q], acc[q]);
        wsum += w;
      }
    }

    const int rem = cnt - full;
    if (rem){
      int  idx[8];
      bool ok[8];
      #pragma unroll
      for (int j = 0; j < 8; ++j){
        int q = csr[s0 + full + j];     // csr has +8 slack
        ok[j]  = j < rem;
        idx[j] = ok[j] ? q : 0;
      }
      float av[8];
      #pragma unroll
      for (int j = 0; j < 8; ++j) av[j] = ASRC[idx[j] * 4 + h];
      uint4 hq[8];
      #pragma unroll
      for (int j = 0; j < 8; ++j) hq[j] = Hv[idx[j] * 16 + cl];
      #pragma unroll
      for (int j = 0; j < 8; ++j){
        float t = av[j] + adst;
        float w = __expf(fmaxf(t, 0.2f * t));
        w = ok[j] ? w : 0.f;
        float f[8];
        unpack8(hq[j], f);
        #pragma unroll
        for (int q = 0; q < 8; ++q) acc[q] = fmaf(w, f[q], acc[q]);
        wsum += w;
      }
    }

    const float inv = 1.f / (wsum + 1e-16f);
    float o[8];
    #pragma unroll
    for (int j = 0; j < 8; ++j){
      float v = acc[j] * inv + bv[j];
      o[j] = v > 0.f ? v : expm1f(v);
    }
    uint4 q;
    q.x = pk_bf2(o[0], o[1]); q.y = pk_bf2(o[2], o[3]);
    q.z = pk_bf2(o[4], o[5]); q.w = pk_bf2(o[6], o[7]);
    *(uint4*)&Ht[row][c0] = q;
  }

  __syncthreads();

  // ---- phase 2: per-wave 16x80 MFMA tile; B direct from global (L1-hot)
  const int lane = tid & 63;
  const int c15  = lane & 15;
  const int quad = lane >> 4;
  const int w    = tid >> 6;                // wave id = row-tile 0..3
  f32x4 a[5];
  #pragma unroll
  for (int ct = 0; ct < 5; ++ct)
    #pragma unroll
    for (int r = 0; r < 4; ++r) a[ct][r] = 0.f;

  #pragma unroll
  for (int kc = 0; kc < 128; kc += 32){
    bf16x8 af = *(const bf16x8*)&Ht[w * 16 + c15][kc + 8 * quad];
    #pragma unroll
    for (int ct = 0; ct < 5; ++ct){
      bf16x8 bfr = *(const bf16x8*)&W2b[(ct * 16 + c15) * 128 + kc + 8 * quad];
      a[ct] = __builtin_amdgcn_mfma_f32_16x16x32_bf16(af, bfr, a[ct], 0, 0, 0);
    }
  }

  #pragma unroll
  for (int r = 0; r < 4; ++r){
    int dd = d0 + w * 16 + quad * 4 + r;
    if (dd < n){
      #pragma unroll
      for (int ct = 0; ct < 4; ++ct)
        H2[(size_t)dd * 64 + ct * 16 + c15] = (unsigned short)f2bf_rne(a[ct][r]);
      float av = a[4][r] + __shfl_xor(a[4][r], 4);
      if (c15 == 0)      AS2[dd] = av;
      else if (c15 == 8) AD2[dd] = av;
    }
  }
}

// ---------------- conv2 aggregate + bias + ELU + fused mean-pool ------------

template<int CH, int HEADS>
__global__ __launch_bounds__(256) void k_agg2_pool(
    const unsigned short* __restrict__ Hmsg, const float* __restrict__ ASRC,
    const float* __restrict__ ADST, const int* __restrict__ off,
    const int* __restrict__ csr, const float* __restrict__ bias,
    const int* __restrict__ batch, float* __restrict__ gsums, int n)
{
  constexpr int CL  = CH / 8;       // 8 lanes per dst
  constexpr int GPB = 256 / CL;     // 32 dsts per block
  constexpr int RQ  = CH / 8;

  __shared__ float lsum[256];

  const int tid = threadIdx.x;
  const int cl  = tid % CL;
  const int c0  = cl * 8;
  const int d   = (int)blockIdx.x * GPB + tid / CL;
  const uint4* Hv = (const uint4*)Hmsg;

  int probe = (int)blockIdx.x * GPB;
  const int gbase = batch[probe < n - 1 ? probe : n - 1];
  lsum[tid] = 0.f;
  __syncthreads();

  float o[8];
  #pragma unroll
  for (int j = 0; j < 8; ++j) o[j] = 0.f;
  int gb = gbase;

  if (d < n){
    gb = batch[d];
    const float adst = ADST[d];

    float acc[8];
    float wsum;
    {
      float t = ASRC[d] + adst;
      float w = __expf(fmaxf(t, 0.2f * t));
      float f[8];
      unpack8(Hv[d * RQ + cl], f);
      #pragma unroll
      for (int j = 0; j < 8; ++j) acc[j] = w * f[j];
      wsum = w;
    }

    const int s0   = off[d];
    const int cnt  = off[d + 1] - s0;
    const int full = cnt & ~7;

    for (int p = 0; p < full; p += 8){
      int idx[8];
      #pragma unroll
      for (int j = 0; j < 8; ++j) idx[j] = csr[s0 + p + j];
      float av[8];
      #pragma unroll
      for (int j = 0; j < 8; ++j) av[j] = ASRC[idx[j]];
      uint4 hq[8];
      #pragma unroll
      for (int j = 0; j < 8; ++j) hq[j] = Hv[idx[j] * RQ + cl];
      #pragma unroll
      for (int j = 0; j < 8; ++j){
        float t = av[j] + adst;
        float w = __expf(fmaxf(t, 0.2f * t));
        float f[8];
        unpack8(hq[j], f);
        #pragma unroll
        for (int q = 0; q < 8; ++q) acc[q] = fmaf(w, f[q], acc[q]);
        wsum += w;
      }
    }

    const int rem = cnt - full;
    if (rem){
      int  idx[8];
      bool ok[8];
      #pragma unroll
      for (int j = 0; j < 8; ++j){
        int q = csr[s0 + full + j];
        ok[j]  = j < rem;
        idx[j] = ok[j] ? q : 0;
      }
      float av[8];
      #pragma unroll
      for (int j = 0; j < 8; ++j) av[j] = ASRC[idx[j]];
      uint4 hq[8];
      #pragma unroll
      for (int j = 0; j < 8; ++j) hq[j] = Hv[idx[j] * RQ + cl];
      #pragma unroll
      for (int j = 0; j < 8; ++j){
        float t = av[j] + adst;
        float w = __expf(fmaxf(t, 0.2f * t));
        w = ok[j] ? w : 0.f;
        float f[8];
        unpack8(hq[j], f);
        #pragma unroll
        for (int q = 0; q < 8; ++q) acc[q] = fmaf(w, f[q], acc[q]);
        wsum += w;
      }
    }

    const float inv = 1.f / (wsum + 1e-16f);
    #pragma unroll
    for (int j = 0; j < 8; ++j){
      float v = acc[j] * inv + bias[c0 + j];
      o[j] = v > 0.f ? v : expm1f(v);
    }
  }

  // ---- pool accumulate
  int gb0 = __shfl(gb, 0, 64);
  bool uni = __all(gb == gb0);
  if (uni){
    #pragma unroll
    for (int s = CL; s < 64; s <<= 1)
      #pragma unroll
      for (int j = 0; j < 8; ++j) o[j] += __shfl_xor(o[j], s);
    if ((tid & 63) < CL){
      int rel = gb0 - gbase;
      if (rel >= 0 && rel < 4){
        #pragma unroll
        for (int j = 0; j < 8; ++j) atomicAdd(&lsum[rel * 64 + c0 + j], o[j]);
      } else {
        #pragma unroll
        for (int j = 0; j < 8; ++j) atomicAdd(&gsums[gb0 * 64 + c0 + j], o[j]);
      }
    }
  } else if (d < n){
    int rel = gb - gbase;
    if (rel >= 0 && rel < 4){
      #pragma unroll
      for (int j = 0; j < 8; ++j) atomicAdd(&lsum[rel * 64 + c0 + j], o[j]);
    } else {
      #pragma unroll
      for (int j = 0; j < 8; ++j) atomicAdd(&gsums[gb * 64 + c0 + j], o[j]);
    }
  }

  __syncthreads();
  int slot = tid >> 6;
  int ch   = tid & 63;
  float v = lsum[slot * 64 + ch];
  int gg = gbase + slot;
  if (v != 0.f && gg < 64)
    atomicAdd(&gsums[gg * 64 + ch], v);
}

__global__ __launch_bounds__(128) void k_classify(
    const float* __restrict__ sums, const int* __restrict__ batch,
    const float* __restrict__ Wc, const float* __restrict__ bc,
    float* __restrict__ out, int n)
{
  int t = threadIdx.x;
  if (t >= 128) return;
  int g = t >> 1, cls = t & 1;
  int lo = 0, hi = n;
  while (lo < hi){ int m = (lo + hi) >> 1; if (batch[m] < g) lo = m + 1; else hi = m; }
  int s = lo;
  lo = s; hi = n;
  while (lo < hi){ int m = (lo + hi) >> 1; if (batch[m] < g + 1) lo = m + 1; else hi = m; }
  int cnt = lo - s;
  float inv = 1.f / (float)(cnt > 1 ? cnt : 1);
  float dot = 0.f;
  #pragma unroll
  for (int c = 0; c < 64; ++c) dot = fmaf(sums[g * 64 + c], Wc[c * 2 + cls], dot);
  out[g * 2 + cls] = dot * inv + bc[cls];
}

// ---------------- launch ----------------

extern "C" void kernel_launch(void* const* d_in, const int* in_sizes, int n_in,
                              void* d_out, int out_size, void* d_ws, size_t ws_size,
                              hipStream_t stream)
{
  const float* x    = (const float*)d_in[0];
  const int*   edge = (const int*)  d_in[1];
  const int*   batch= (const int*)  d_in[2];
  const float* W1   = (const float*)d_in[3];
  const float* as1w = (const float*)d_in[4];
  const float* ad1w = (const float*)d_in[5];
  const float* b1   = (const float*)d_in[6];
  const float* W2   = (const float*)d_in[7];
  const float* as2w = (const float*)d_in[8];
  const float* ad2w = (const float*)d_in[9];
  const float* b2   = (const float*)d_in[10];
  const float* Wc   = (const float*)d_in[11];
  const float* bc   = (const float*)d_in[12];

  const int n = in_sizes[2];          // 100000
  const int e = in_sizes[1] / 2;      // 1600000
  const int* esrc = edge;
  const int* edst = edge + e;
  const int NB = (n + 255) >> 8;      // 391 buckets

  // workspace layout
  unsigned short* h1  = (unsigned short*)d_ws;              // n*128 bf16
  unsigned short* h2  = h1 + (size_t)n * 128;               // n*64 bf16
  float* as1 = (float*)(h2 + (size_t)n * 64);               // n*4
  float* ad1 = as1 + (size_t)n * 4;                         // n*4
  float* as2 = ad1 + (size_t)n * 4;                         // n
  float* ad2 = as2 + (size_t)n;                             // n
  float* sums = ad2 + (size_t)n;                            // 64*64
  unsigned short* wa1 = (unsigned short*)(sums + 64 * 64);  // [16][128] bf16
  unsigned short* w2b = wa1 + 2048;                         // [80][128] bf16
  int*  bcnt  = (int*)(w2b + 80 * 128);                     // 512
  int*  cur   = bcnt + 512;                                 // 512
  int*  bbase = cur + 512;                                  // 512
  int*  off   = bbase + 512;                                // n+1
  unsigned* packed = (unsigned*)(off + n + 1);              // e
  int*  csr   = (int*)(packed + e);                         // e + 8 slack

  const int eb = (e + CHUNKE - 1) / CHUNKE;                 // 391 blocks

  // zero: sums + wa1 + w2b + bcnt (contiguous)
  (void)hipMemsetAsync(sums, 0, 64 * 64 * 4 + 2048 * 2 + 80 * 128 * 2 + 512 * 4, stream);
  k_bucketcount<<<eb, 256, 0, stream>>>(edst, bcnt, e, NB);
  k_bucketscan <<<2, 512, 0, stream>>>(bcnt, bbase, cur, off, e, n, NB,
                                       W1, as1w, ad1w, W2, as2w, ad2w, wa1, w2b);
  k_partition  <<<eb, 256, 0, stream>>>(esrc, edst, cur, packed, e, NB);
  k_bucketbuild<<<NB, 256, 0, stream>>>(packed, bbase, bcnt, off, csr, n);

  // conv1 GEMM (MFMA, 128 rows/block)
  k_gemm_mfma<128, 4, false><<<(n + 127) / 128, 256, 0, stream>>>(
      x, W1, wa1, h1, as1, ad1, n);

  // conv1 aggregate + fused conv2 GEMM (64-dst supertile)
  k_agg1_fused<<<(n + 63) / 64, 256, 0, stream>>>(
      h1, as1, ad1, off, csr, b1, w2b, h2, as2, ad2, n);

  // conv2 aggregate + fused mean-pool
  k_agg2_pool<64, 1><<<(n + 31) / 32, 256, 0, stream>>>(
      h2, as2, ad2, off, csr, b2, batch, sums, n);

  // classify
  k_classify<<<1, 128, 0, stream>>>(sums, batch, Wc, bc, (float*)d_out, n);
}

// Round 9
// 341.142 us; speedup vs baseline: 1.0412x; 1.0412x over previous
//
#include <hip/hip_runtime.h>
#include <math.h>

// ---------------------------------------------------------------------------
// GAT 2-layer + mean-pool + classifier.
//  - CSR(dst): bucketed two-pass build (multisplit), LDS-staged coalesced
//    partition (R2).  CHUNKE 4096 (R8, kept: ~-4us).
//  - aggregation: ONE 16-lane group per dst-row (R1 config)
//  - gemm2 fused into agg1 (R6), 64-dst supertile (R7).  R9: 512-thread
//    blocks (8 waves) -- R8 diagnosis: occupancy was queue-depth-limited
//    (1563 blocks x 4 waves = 6/CU), NOT LDS-limited; global-B MFMA reads
//    (R8) reverted to LDS Bs2.
//  - Pool via wave shuffle butterfly (R6).
//  - GEMM1: MFMA 16x16x32 bf16; a_src/a_dst folded as extra B columns
//    (bf16 hi/lo split, R3).
// ---------------------------------------------------------------------------

typedef __attribute__((ext_vector_type(8))) short bf16x8;
typedef __attribute__((ext_vector_type(4))) float f32x4;

__device__ __forceinline__ unsigned f2bf_rne(float x){
  unsigned u = __float_as_uint(x);
  return (u + 0x7fffu + ((u >> 16) & 1u)) >> 16;
}
__device__ __forceinline__ unsigned pk_bf2(float a, float b){
  return f2bf_rne(a) | (f2bf_rne(b) << 16);
}
__device__ __forceinline__ void unpack8(uint4 q, float* f){
  f[0] = __uint_as_float(q.x << 16);
  f[1] = __uint_as_float(q.x & 0xffff0000u);
  f[2] = __uint_as_float(q.y << 16);
  f[3] = __uint_as_float(q.y & 0xffff0000u);
  f[4] = __uint_as_float(q.z << 16);
  f[5] = __uint_as_float(q.z & 0xffff0000u);
  f[6] = __uint_as_float(q.w << 16);
  f[7] = __uint_as_float(q.w & 0xffff0000u);
}

// ---------------- bucketed CSR build ----------------

#define CHUNKE 4096

__global__ __launch_bounds__(256) void k_bucketcount(
    const int* __restrict__ dst, int* __restrict__ bcnt, int e, int NB)
{
  __shared__ int hcnt[512];
  const int tid = threadIdx.x;
  for (int b = tid; b < 512; b += 256) hcnt[b] = 0;
  __syncthreads();
  const int lo = blockIdx.x * CHUNKE;
  const int hi = min(lo + CHUNKE, e);
  for (int i = lo + tid; i < hi; i += 256)
    atomicAdd(&hcnt[dst[i] >> 8], 1);
  __syncthreads();
  for (int b = tid; b < NB; b += 256)
    if (hcnt[b]) atomicAdd(&bcnt[b], hcnt[b]);
}

// block 0: bucket scan.  block 1: wa1 att columns + W2b [80][128] bf16.
__global__ __launch_bounds__(512) void k_bucketscan(
    const int* __restrict__ bcnt, int* __restrict__ bbase,
    int* __restrict__ cur, int* __restrict__ off, int e, int n, int NB,
    const float* __restrict__ W1, const float* __restrict__ as1w,
    const float* __restrict__ ad1w,
    const float* __restrict__ W2, const float* __restrict__ as2w,
    const float* __restrict__ ad2w,
    unsigned short* __restrict__ wa1, unsigned short* __restrict__ w2b)
{
  const int t = threadIdx.x;

  if (blockIdx.x == 1){
    for (int i = t; i < 16 * 128; i += 512) w2b[64 * 128 + i] = 0;
    __syncthreads();
    {
      int k = t >> 2, j = t & 3;
      float ds = 0.f, dd = 0.f;
      for (int cc = 0; cc < 32; ++cc){
        float wv = W1[k * 128 + j * 32 + cc];
        ds = fmaf(wv, as1w[j * 32 + cc], ds);
        dd = fmaf(wv, ad1w[j * 32 + cc], dd);
      }
      unsigned hs_ = f2bf_rne(ds); float hsf = __uint_as_float(hs_ << 16);
      unsigned ls_ = f2bf_rne(ds - hsf);
      unsigned hd_ = f2bf_rne(dd); float hdf = __uint_as_float(hd_ << 16);
      unsigned ld_ = f2bf_rne(dd - hdf);
      wa1[(j     ) * 128 + k] = (unsigned short)hs_;
      wa1[(j + 4 ) * 128 + k] = (unsigned short)ls_;
      wa1[(j + 8 ) * 128 + k] = (unsigned short)hd_;
      wa1[(j + 12) * 128 + k] = (unsigned short)ld_;
    }
    for (int idx = t; idx < 64 * 128; idx += 512){
      int col = idx & 63, k = idx >> 6;
      w2b[col * 128 + k] = (unsigned short)f2bf_rne(W2[k * 64 + col]);
    }
    if (t < 128){
      int k = t;
      float ds = 0.f, dd = 0.f;
      for (int cc = 0; cc < 64; ++cc){
        float wv = W2[k * 64 + cc];
        ds = fmaf(wv, as2w[cc], ds);
        dd = fmaf(wv, ad2w[cc], dd);
      }
      unsigned hs_ = f2bf_rne(ds); float hsf = __uint_as_float(hs_ << 16);
      unsigned ls_ = f2bf_rne(ds - hsf);
      unsigned hd_ = f2bf_rne(dd); float hdf = __uint_as_float(hd_ << 16);
      unsigned ld_ = f2bf_rne(dd - hdf);
      w2b[(64 +  0) * 128 + k] = (unsigned short)hs_;
      w2b[(64 +  4) * 128 + k] = (unsigned short)ls_;
      w2b[(64 +  8) * 128 + k] = (unsigned short)hd_;
      w2b[(64 + 12) * 128 + k] = (unsigned short)ld_;
    }
    return;
  }

  __shared__ int sh[512];
  int v = (t < NB) ? bcnt[t] : 0;
  sh[t] = v;
  __syncthreads();
  for (int o = 1; o < 512; o <<= 1){
    int x = (t >= o) ? sh[t - o] : 0;
    __syncthreads();
    sh[t] += x;
    __syncthreads();
  }
  if (t < NB){
    int excl = sh[t] - v;
    bbase[t] = excl;
    cur[t]   = excl;
  }
  if (t == 0) off[n] = e;
}

// LDS-staged multisplit partition (coalesced writeout).
__global__ __launch_bounds__(256) void k_partition(
    const int* __restrict__ src, const int* __restrict__ dst,
    int* __restrict__ cur, unsigned* __restrict__ packed, int e, int NB)
{
  __shared__ unsigned       recs[CHUNKE];   // 16 KB
  __shared__ unsigned short bkt[CHUNKE];    //  8 KB
  __shared__ int hcnt[512];
  __shared__ int hoff[512];
  __shared__ int hbase[512];

  const int tid = threadIdx.x;
  const int lo  = blockIdx.x * CHUNKE;
  const int hi  = min(lo + CHUNKE, e);
  const int cnt = hi - lo;

  hcnt[tid] = 0; hcnt[tid + 256] = 0;
  __syncthreads();
  for (int i = lo + tid; i < hi; i += 256)
    atomicAdd(&hcnt[dst[i] >> 8], 1);
  __syncthreads();

  hoff[tid] = hcnt[tid]; hoff[tid + 256] = hcnt[tid + 256];
  __syncthreads();
  for (int o = 1; o < 512; o <<= 1){
    int x0 = (tid >= o)       ? hoff[tid - o]       : 0;
    int x1 = (tid + 256 >= o) ? hoff[tid + 256 - o] : 0;
    __syncthreads();
    hoff[tid] += x0; hoff[tid + 256] += x1;
    __syncthreads();
  }

  int c0 = hcnt[tid], c1 = hcnt[tid + 256];
  int e0 = hoff[tid] - c0, e1 = hoff[tid + 256] - c1;
  hbase[tid]       = c0 ? atomicAdd(&cur[tid], c0)       : 0;
  hbase[tid + 256] = c1 ? atomicAdd(&cur[tid + 256], c1) : 0;
  __syncthreads();
  hoff[tid] = e0; hoff[tid + 256] = e1;
  hcnt[tid] = 0;  hcnt[tid + 256] = 0;
  __syncthreads();

  for (int i = lo + tid; i < hi; i += 256){
    int d = dst[i];
    int b = d >> 8;
    int p = hoff[b] + atomicAdd(&hcnt[b], 1);
    recs[p] = (unsigned)src[i] | ((unsigned)(d & 255) << 17);
    bkt[p]  = (unsigned short)b;
  }
  __syncthreads();

  for (int t = tid; t < cnt; t += 256){
    int b = bkt[t];
    packed[hbase[b] + t - hoff[b]] = recs[t];
  }
}

__global__ __launch_bounds__(256) void k_bucketbuild(
    const unsigned* __restrict__ packed, const int* __restrict__ bbase,
    const int* __restrict__ bcnt, int* __restrict__ off,
    int* __restrict__ csr, int n)
{
  __shared__ int lcnt[256];
  __shared__ int loff[256];
  const int b    = blockIdx.x;
  const int tid  = threadIdx.x;
  const int seg0 = bbase[b];
  const int scnt = bcnt[b];

  lcnt[tid] = 0;
  __syncthreads();
  for (int i = tid; i < scnt; i += 256)
    atomicAdd(&lcnt[packed[seg0 + i] >> 17], 1);
  __syncthreads();
  int v = lcnt[tid];
  loff[tid] = v;
  __syncthreads();
  for (int o = 1; o < 256; o <<= 1){
    int x = (tid >= o) ? loff[tid - o] : 0;
    __syncthreads();
    loff[tid] += x;
    __syncthreads();
  }
  int excl = loff[tid] - v;
  __syncthreads();
  loff[tid] = excl;
  lcnt[tid] = 0;
  int d = (b << 8) + tid;
  if (d < n) off[d] = seg0 + excl;
  __syncthreads();
  for (int i = tid; i < scnt; i += 256){
    unsigned rec = packed[seg0 + i];
    int doff = rec >> 17;
    int s    = rec & 0x1FFFF;
    int p    = atomicAdd(&lcnt[doff], 1);
    csr[seg0 + loff[doff] + p] = s;
  }
}

// ---------------- MFMA GEMM (X @ W | W@att columns) -- conv1 ----------------

template<int OUTC, int HEADS, bool XBF16, typename XT>
__global__ __launch_bounds__(256) void k_gemm_mfma(
    const XT* __restrict__ X, const float* __restrict__ W,
    const unsigned short* __restrict__ WATT,
    unsigned short* __restrict__ H, float* __restrict__ ASRC,
    float* __restrict__ ADST, int n)
{
  constexpr int K  = 128;
  constexpr int KC = 32;
  constexpr int CT = OUTC / 16;
  constexpr int CTX = CT + 1;
  constexpr int RT = 16 / CT;
  constexpr int WROWS = RT * 16;
  constexpr int BROWS = WROWS * 4;

  __shared__ unsigned short Bs[OUTC + 16][K + 8];
  __shared__ unsigned short As[BROWS][KC + 8];

  const int tid   = threadIdx.x;
  const int lane  = tid & 63;
  const int c15   = lane & 15;
  const int quad  = lane >> 4;
  const int warow = (tid >> 6) * WROWS;
  const int row0  = blockIdx.x * BROWS;

  f32x4 acc[CTX][RT];
  #pragma unroll
  for (int ct = 0; ct < CTX; ++ct)
    #pragma unroll
    for (int t = 0; t < RT; ++t)
      #pragma unroll
      for (int r = 0; r < 4; ++r) acc[ct][t][r] = 0.f;

  for (int idx = tid; idx < K * OUTC / 4; idx += 256){
    int k  = idx / (OUTC / 4);
    int c4 = (idx % (OUTC / 4)) * 4;
    float4 v = *(const float4*)&W[(size_t)k * OUTC + c4];
    Bs[c4 + 0][k] = (unsigned short)f2bf_rne(v.x);
    Bs[c4 + 1][k] = (unsigned short)f2bf_rne(v.y);
    Bs[c4 + 2][k] = (unsigned short)f2bf_rne(v.z);
    Bs[c4 + 3][k] = (unsigned short)f2bf_rne(v.w);
  }
  for (int idx = tid; idx < 16 * (K / 8); idx += 256){
    int rr = idx >> 4;
    int q  = idx & 15;
    *(uint4*)&Bs[OUTC + rr][q * 8] = *(const uint4*)&WATT[rr * K + q * 8];
  }

  for (int kc = 0; kc < K; kc += KC){
    if (XBF16){
      for (int idx = tid; idx < BROWS * (KC / 8); idx += 256){
        int rr = idx / (KC / 8);
        int q  = idx % (KC / 8);
        int row = row0 + rr;
        uint4 v = make_uint4(0, 0, 0, 0);
        if (row < n) v = *(const uint4*)((const unsigned short*)X + (size_t)row * K + kc + q * 8);
        *(uint4*)&As[rr][q * 8] = v;
      }
    } else {
      for (int idx = tid; idx < BROWS * (KC / 4); idx += 256){
        int rr = idx / (KC / 4);
        int q  = idx % (KC / 4);
        int row = row0 + rr;
        float4 v = make_float4(0.f, 0.f, 0.f, 0.f);
        if (row < n) v = *(const float4*)((const float*)X + (size_t)row * K + kc + q * 4);
        *(uint2*)&As[rr][q * 4] = make_uint2(pk_bf2(v.x, v.y), pk_bf2(v.z, v.w));
      }
    }
    __syncthreads();

    bf16x8 af[RT];
    #pragma unroll
    for (int t = 0; t < RT; ++t)
      af[t] = *(const bf16x8*)&As[warow + t * 16 + c15][8 * quad];
    #pragma unroll
    for (int ct = 0; ct < CTX; ++ct){
      bf16x8 bfr = *(const bf16x8*)&Bs[ct * 16 + c15][kc + 8 * quad];
      #pragma unroll
      for (int t = 0; t < RT; ++t)
        acc[ct][t] = __builtin_amdgcn_mfma_f32_16x16x32_bf16(af[t], bfr, acc[ct][t], 0, 0, 0);
    }
    __syncthreads();
  }

  #pragma unroll
  for (int t = 0; t < RT; ++t){
    #pragma unroll
    for (int r = 0; r < 4; ++r){
      int row = row0 + warow + t * 16 + quad * 4 + r;
      float av = acc[CT][t][r];
      av += __shfl_xor(av, 4);
      if (row < n){
        #pragma unroll
        for (int ct = 0; ct < CT; ++ct)
          H[(size_t)row * OUTC + ct * 16 + c15] = (unsigned short)f2bf_rne(acc[ct][t][r]);
        if (c15 < HEADS)                      ASRC[row * HEADS + c15] = av;
        else if (c15 >= 8 && c15 < 8 + HEADS) ADST[row * HEADS + c15 - 8] = av;
      }
    }
  }
}

// ---------------- conv1 aggregate + bias + ELU + FUSED conv2 GEMM ----------
// R9: 512-thread block, 64-dst supertile.  Phase 1: 32 groups x 2 dsts ->
// elu'd rows of Ht[64][136]; Bs2 staged once.  ONE barrier.  Phase 2: 20
// MFMA tiles (4 row x 5 col) split over 8 waves.

__global__ __launch_bounds__(512) void k_agg1_fused(
    const unsigned short* __restrict__ Hmsg, const float* __restrict__ ASRC,
    const float* __restrict__ ADST, const int* __restrict__ off,
    const int* __restrict__ csr, const float* __restrict__ bias,
    const unsigned short* __restrict__ W2b,
    unsigned short* __restrict__ H2, float* __restrict__ AS2,
    float* __restrict__ AD2, int n)
{
  __shared__ unsigned short Ht[64][136];
  __shared__ unsigned short Bs2[80][136];

  const int tid = threadIdx.x;
  const int cl  = tid & 15;
  const int c0  = cl * 8;
  const int h   = cl >> 2;                  // c0 / 32
  const int ld  = tid >> 4;                 // 0..31
  const int d0  = (int)blockIdx.x * 64;
  const uint4* Hv = (const uint4*)Hmsg;

  // stage W2ex once per block
  for (int idx = tid; idx < 80 * 16; idx += 512){
    int row = idx >> 4, q = idx & 15;
    *(uint4*)&Bs2[row][q * 8] = *(const uint4*)&W2b[row * 128 + q * 8];
  }

  float bv[8];
  #pragma unroll
  for (int j = 0; j < 8; ++j) bv[j] = bias[c0 + j];

  #pragma unroll 1
  for (int it = 0; it < 2; ++it){
    const int row = it * 32 + ld;
    const int d   = d0 + row;
    if (d >= n) break;

    const float adst = ADST[d * 4 + h];

    float acc[8];
    float wsum;
    {
      float t = ASRC[d * 4 + h] + adst;
      float w = __expf(fmaxf(t, 0.2f * t));
      float f[8];
      unpack8(Hv[d * 16 + cl], f);
      #pragma unroll
      for (int j = 0; j < 8; ++j) acc[j] = w * f[j];
      wsum = w;
    }

    const int s0   = off[d];
    const int cnt  = off[d + 1] - s0;
    const int full = cnt & ~7;

    for (int p = 0; p < full; p += 8){
      int idx[8];
      #pragma unroll
      for (int j = 0; j < 8; ++j) idx[j] = csr[s0 + p + j];
      float av[8];
      #pragma unroll
      for (int j = 0; j < 8; ++j) av[j] = ASRC[idx[j] * 4 + h];
      uint4 hq[8];
      #pragma unroll
      for (int j = 0; j < 8; ++j) hq[j] = Hv[idx[j] * 16 + cl];
      #pragma unroll
      for (int j = 0; j < 8; ++j){
        float t = av[j] + adst;
        float w = __expf(fmaxf(t, 0.2f * t));
        float f[8];
        unpack8(hq[j], f);
        #pragma unroll
        for (int q = 0; q < 8; ++q) acc[q] = fmaf(w, f[q], acc[q]);
        wsum += w;
      }
    }

    const int rem = cnt - full;
    if (rem){
      int  idx[8];
      bool ok[8];
      #pragma unroll
      for (int j = 0; j < 8; ++j){
        int q = csr[s0 + full + j];     // csr has +8 slack
        ok[j]  = j < rem;
        idx[j] = ok[j] ? q : 0;
      }
      float av[8];
      #pragma unroll
      for (int j = 0; j < 8; ++j) av[j] = ASRC[idx[j] * 4 + h];
      uint4 hq[8];
      #pragma unroll
      for (int j = 0; j < 8; ++j) hq[j] = Hv[idx[j] * 16 + cl];
      #pragma unroll
      for (int j = 0; j < 8; ++j){
        float t = av[j] + adst;
        float w = __expf(fmaxf(t, 0.2f * t));
        w = ok[j] ? w : 0.f;
        float f[8];
        unpack8(hq[j], f);
        #pragma unroll
        for (int q = 0; q < 8; ++q) acc[q] = fmaf(w, f[q], acc[q]);
        wsum += w;
      }
    }

    const float inv = 1.f / (wsum + 1e-16f);
    float o[8];
    #pragma unroll
    for (int j = 0; j < 8; ++j){
      float v = acc[j] * inv + bv[j];
      o[j] = v > 0.f ? v : expm1f(v);
    }
    uint4 q;
    q.x = pk_bf2(o[0], o[1]); q.y = pk_bf2(o[2], o[3]);
    q.z = pk_bf2(o[4], o[5]); q.w = pk_bf2(o[6], o[7]);
    *(uint4*)&Ht[row][c0] = q;
  }

  __syncthreads();

  // ---- phase 2: 20 MFMA tiles over 8 waves
  const int lane = tid & 63;
  const int c15  = lane & 15;
  const int quad = lane >> 4;
  const int w    = tid >> 6;                // 0..7

  #pragma unroll 1
  for (int t = w; t < 20; t += 8){
    const int rt = t / 5, ct = t % 5;
    f32x4 a;
    #pragma unroll
    for (int r = 0; r < 4; ++r) a[r] = 0.f;
    #pragma unroll
    for (int kc = 0; kc < 128; kc += 32){
      bf16x8 af  = *(const bf16x8*)&Ht[rt * 16 + c15][kc + 8 * quad];
      bf16x8 bfr = *(const bf16x8*)&Bs2[ct * 16 + c15][kc + 8 * quad];
      a = __builtin_amdgcn_mfma_f32_16x16x32_bf16(af, bfr, a, 0, 0, 0);
    }
    #pragma unroll
    for (int r = 0; r < 4; ++r){
      int dd = d0 + rt * 16 + quad * 4 + r;
      if (dd < n){
        if (ct < 4){
          H2[(size_t)dd * 64 + ct * 16 + c15] = (unsigned short)f2bf_rne(a[r]);
        } else {
          float av = a[r] + __shfl_xor(a[r], 4);
          if (c15 == 0)      AS2[dd] = av;
          else if (c15 == 8) AD2[dd] = av;
        }
      }
    }
  }
}

// ---------------- conv2 aggregate + bias + ELU + fused mean-pool ------------

template<int CH, int HEADS>
__global__ __launch_bounds__(256) void k_agg2_pool(
    const unsigned short* __restrict__ Hmsg, const float* __restrict__ ASRC,
    const float* __restrict__ ADST, const int* __restrict__ off,
    const int* __restrict__ csr, const float* __restrict__ bias,
    const int* __restrict__ batch, float* __restrict__ gsums, int n)
{
  constexpr int CL  = CH / 8;       // 8 lanes per dst
  constexpr int GPB = 256 / CL;     // 32 dsts per block
  constexpr int RQ  = CH / 8;

  __shared__ float lsum[256];

  const int tid = threadIdx.x;
  const int cl  = tid % CL;
  const int c0  = cl * 8;
  const int d   = (int)blockIdx.x * GPB + tid / CL;
  const uint4* Hv = (const uint4*)Hmsg;

  int probe = (int)blockIdx.x * GPB;
  const int gbase = batch[probe < n - 1 ? probe : n - 1];
  lsum[tid] = 0.f;
  __syncthreads();

  float o[8];
  #pragma unroll
  for (int j = 0; j < 8; ++j) o[j] = 0.f;
  int gb = gbase;

  if (d < n){
    gb = batch[d];
    const float adst = ADST[d];

    float acc[8];
    float wsum;
    {
      float t = ASRC[d] + adst;
      float w = __expf(fmaxf(t, 0.2f * t));
      float f[8];
      unpack8(Hv[d * RQ + cl], f);
      #pragma unroll
      for (int j = 0; j < 8; ++j) acc[j] = w * f[j];
      wsum = w;
    }

    const int s0   = off[d];
    const int cnt  = off[d + 1] - s0;
    const int full = cnt & ~7;

    for (int p = 0; p < full; p += 8){
      int idx[8];
      #pragma unroll
      for (int j = 0; j < 8; ++j) idx[j] = csr[s0 + p + j];
      float av[8];
      #pragma unroll
      for (int j = 0; j < 8; ++j) av[j] = ASRC[idx[j]];
      uint4 hq[8];
      #pragma unroll
      for (int j = 0; j < 8; ++j) hq[j] = Hv[idx[j] * RQ + cl];
      #pragma unroll
      for (int j = 0; j < 8; ++j){
        float t = av[j] + adst;
        float w = __expf(fmaxf(t, 0.2f * t));
        float f[8];
        unpack8(hq[j], f);
        #pragma unroll
        for (int q = 0; q < 8; ++q) acc[q] = fmaf(w, f[q], acc[q]);
        wsum += w;
      }
    }

    const int rem = cnt - full;
    if (rem){
      int  idx[8];
      bool ok[8];
      #pragma unroll
      for (int j = 0; j < 8; ++j){
        int q = csr[s0 + full + j];
        ok[j]  = j < rem;
        idx[j] = ok[j] ? q : 0;
      }
      float av[8];
      #pragma unroll
      for (int j = 0; j < 8; ++j) av[j] = ASRC[idx[j]];
      uint4 hq[8];
      #pragma unroll
      for (int j = 0; j < 8; ++j) hq[j] = Hv[idx[j] * RQ + cl];
      #pragma unroll
      for (int j = 0; j < 8; ++j){
        float t = av[j] + adst;
        float w = __expf(fmaxf(t, 0.2f * t));
        w = ok[j] ? w : 0.f;
        float f[8];
        unpack8(hq[j], f);
        #pragma unroll
        for (int q = 0; q < 8; ++q) acc[q] = fmaf(w, f[q], acc[q]);
        wsum += w;
      }
    }

    const float inv = 1.f / (wsum + 1e-16f);
    #pragma unroll
    for (int j = 0; j < 8; ++j){
      float v = acc[j] * inv + bias[c0 + j];
      o[j] = v > 0.f ? v : expm1f(v);
    }
  }

  // ---- pool accumulate
  int gb0 = __shfl(gb, 0, 64);
  bool uni = __all(gb == gb0);
  if (uni){
    #pragma unroll
    for (int s = CL; s < 64; s <<= 1)
      #pragma unroll
      for (int j = 0; j < 8; ++j) o[j] += __shfl_xor(o[j], s);
    if ((tid & 63) < CL){
      int rel = gb0 - gbase;
      if (rel >= 0 && rel < 4){
        #pragma unroll
        for (int j = 0; j < 8; ++j) atomicAdd(&lsum[rel * 64 + c0 + j], o[j]);
      } else {
        #pragma unroll
        for (int j = 0; j < 8; ++j) atomicAdd(&gsums[gb0 * 64 + c0 + j], o[j]);
      }
    }
  } else if (d < n){
    int rel = gb - gbase;
    if (rel >= 0 && rel < 4){
      #pragma unroll
      for (int j = 0; j < 8; ++j) atomicAdd(&lsum[rel * 64 + c0 + j], o[j]);
    } else {
      #pragma unroll
      for (int j = 0; j < 8; ++j) atomicAdd(&gsums[gb * 64 + c0 + j], o[j]);
    }
  }

  __syncthreads();
  int slot = tid >> 6;
  int ch   = tid & 63;
  float v = lsum[slot * 64 + ch];
  int gg = gbase + slot;
  if (v != 0.f && gg < 64)
    atomicAdd(&gsums[gg * 64 + ch], v);
}

__global__ __launch_bounds__(128) void k_classify(
    const float* __restrict__ sums, const int* __restrict__ batch,
    const float* __restrict__ Wc, const float* __restrict__ bc,
    float* __restrict__ out, int n)
{
  int t = threadIdx.x;
  if (t >= 128) return;
  int g = t >> 1, cls = t & 1;
  int lo = 0, hi = n;
  while (lo < hi){ int m = (lo + hi) >> 1; if (batch[m] < g) lo = m + 1; else hi = m; }
  int s = lo;
  lo = s; hi = n;
  while (lo < hi){ int m = (lo + hi) >> 1; if (batch[m] < g + 1) lo = m + 1; else hi = m; }
  int cnt = lo - s;
  float inv = 1.f / (float)(cnt > 1 ? cnt : 1);
  float dot = 0.f;
  #pragma unroll
  for (int c = 0; c < 64; ++c) dot = fmaf(sums[g * 64 + c], Wc[c * 2 + cls], dot);
  out[g * 2 + cls] = dot * inv + bc[cls];
}

// ---------------- launch ----------------

extern "C" void kernel_launch(void* const* d_in, const int* in_sizes, int n_in,
                              void* d_out, int out_size, void* d_ws, size_t ws_size,
                              hipStream_t stream)
{
  const float* x    = (const float*)d_in[0];
  const int*   edge = (const int*)  d_in[1];
  const int*   batch= (const int*)  d_in[2];
  const float* W1   = (const float*)d_in[3];
  const float* as1w = (const float*)d_in[4];
  const float* ad1w = (const float*)d_in[5];
  const float* b1   = (const float*)d_in[6];
  const float* W2   = (const float*)d_in[7];
  const float* as2w = (const float*)d_in[8];
  const float* ad2w = (const float*)d_in[9];
  const float* b2   = (const float*)d_in[10];
  const float* Wc   = (const float*)d_in[11];
  const float* bc   = (const float*)d_in[12];

  const int n = in_sizes[2];          // 100000
  const int e = in_sizes[1] / 2;      // 1600000
  const int* esrc = edge;
  const int* edst = edge + e;
  const int NB = (n + 255) >> 8;      // 391 buckets

  // workspace layout
  unsigned short* h1  = (unsigned short*)d_ws;              // n*128 bf16
  unsigned short* h2  = h1 + (size_t)n * 128;               // n*64 bf16
  float* as1 = (float*)(h2 + (size_t)n * 64);               // n*4
  float* ad1 = as1 + (size_t)n * 4;                         // n*4
  float* as2 = ad1 + (size_t)n * 4;                         // n
  float* ad2 = as2 + (size_t)n;                             // n
  float* sums = ad2 + (size_t)n;                            // 64*64
  unsigned short* wa1 = (unsigned short*)(sums + 64 * 64);  // [16][128] bf16
  unsigned short* w2b = wa1 + 2048;                         // [80][128] bf16
  int*  bcnt  = (int*)(w2b + 80 * 128);                     // 512
  int*  cur   = bcnt + 512;                                 // 512
  int*  bbase = cur + 512;                                  // 512
  int*  off   = bbase + 512;                                // n+1
  unsigned* packed = (unsigned*)(off + n + 1);              // e
  int*  csr   = (int*)(packed + e);                         // e + 8 slack

  const int eb = (e + CHUNKE - 1) / CHUNKE;                 // 391 blocks

  // zero: sums + wa1 + w2b + bcnt (contiguous)
  (void)hipMemsetAsync(sums, 0, 64 * 64 * 4 + 2048 * 2 + 80 * 128 * 2 + 512 * 4, stream);
  k_bucketcount<<<eb, 256, 0, stream>>>(edst, bcnt, e, NB);
  k_bucketscan <<<2, 512, 0, stream>>>(bcnt, bbase, cur, off, e, n, NB,
                                       W1, as1w, ad1w, W2, as2w, ad2w, wa1, w2b);
  k_partition  <<<eb, 256, 0, stream>>>(esrc, edst, cur, packed, e, NB);
  k_bucketbuild<<<NB, 256, 0, stream>>>(packed, bbase, bcnt, off, csr, n);

  // conv1 GEMM (MFMA, 128 rows/block)
  k_gemm_mfma<128, 4, false><<<(n + 127) / 128, 256, 0, stream>>>(
      x, W1, wa1, h1, as1, ad1, n);

  // conv1 aggregate + fused conv2 GEMM (64-dst supertile, 8 waves)
  k_agg1_fused<<<(n + 63) / 64, 512, 0, stream>>>(
      h1, as1, ad1, off, csr, b1, w2b, h2, as2, ad2, n);

  // conv2 aggregate + fused mean-pool
  k_agg2_pool<64, 1><<<(n + 31) / 32, 256, 0, stream>>>(
      h2, as2, ad2, off, csr, b2, batch, sums, n);

  // classify
  k_classify<<<1, 128, 0, stream>>>(sums, batch, Wc, bc, (float*)d_out, n);
}